// Round 5
// baseline (118.665 us; speedup 1.0000x reference)
//
#include <hip/hip_runtime.h>
#include <hip/hip_bf16.h>

typedef __bf16 bf16x8 __attribute__((ext_vector_type(8)));
typedef float f32x4 __attribute__((ext_vector_type(4)));

#define GN    1024
#define BATCH 64
#define CIN   256
#define COUT  256
#define WSLICE 4096  // per wave, per buffer: 32 o-rows x 32 k x 4B

#define G_AS __attribute__((address_space(1)))
#define L_AS __attribute__((address_space(3)))

static __device__ __forceinline__ void gload16(const void* g, void* l) {
  __builtin_amdgcn_global_load_lds((const G_AS void*)g, (L_AS void*)l, 16, 0, 0);
}

static __device__ __forceinline__ ushort f2bf(float f) {
  __hip_bfloat16 h = __float2bfloat16(f);
  return *reinterpret_cast<ushort*>(&h);
}
static __device__ __forceinline__ float bf2f(ushort u) {
  uint v = (uint)u << 16;
  return *reinterpret_cast<float*>(&v);
}

// ---------------------------------------------------------------------------
// Kernel 1: transpose + convert  x[b][i][g] (f32) -> xT[b][g][i^((b&7)<<3)] (bf16)
// xT stored PRE-SWIZZLED in i so k2 can DMA it linearly (rule 21).
// ---------------------------------------------------------------------------
__global__ __launch_bounds__(256) void k_transpose_convert(
    const float* __restrict__ x, ushort* __restrict__ xT)
{
  __shared__ float tile[64][65];
  const int g0 = blockIdx.x * 64;
  const int i0 = blockIdx.y * 64;
  const int b  = blockIdx.z;
  const int t  = threadIdx.x;
  const int a  = t & 15;
  const int r  = t >> 4;
  const int key = (b & 7) << 3;

  const float* xb = x + (size_t)b * CIN * GN;
#pragma unroll
  for (int p = 0; p < 4; ++p) {
    int ii = p * 16 + r;
    float4 v = *reinterpret_cast<const float4*>(
        &xb[(size_t)(i0 + ii) * GN + g0 + a * 4]);
    tile[ii][a * 4 + 0] = v.x;
    tile[ii][a * 4 + 1] = v.y;
    tile[ii][a * 4 + 2] = v.z;
    tile[ii][a * 4 + 3] = v.w;
  }
  __syncthreads();

  ushort* xTb = xT + (size_t)b * GN * CIN;
#pragma unroll
  for (int p = 0; p < 4; ++p) {
    int gg = p * 16 + r;
    ushort4 u;
    u.x = f2bf(tile[a * 4 + 0][gg]);
    u.y = f2bf(tile[a * 4 + 1][gg]);
    u.z = f2bf(tile[a * 4 + 2][gg]);
    u.w = f2bf(tile[a * 4 + 3][gg]);
    int isw = (i0 + a * 4) ^ key;
    *reinterpret_cast<ushort4*>(&xTb[(size_t)(g0 + gg) * CIN + isw]) = u;
  }
}

// ---------------------------------------------------------------------------
// Kernel 2: per-group GEMM, DMA-streamed, 64 KB LDS -> 2 blocks/CU.
// One block per g; wave w owns o in [64w, 64w+64), processed in two
// 32-o halves so W slices are 4 KB (dbuf 8 KB/wave).
// Counted per-wave vmcnt pacing, no barriers in the K-loop.
// ---------------------------------------------------------------------------
__global__ __launch_bounds__(256, 2) void k_group_gemm(
    const ushort* __restrict__ xT, const float* __restrict__ W,
    const float* __restrict__ bias, float* __restrict__ out,
    ushort* __restrict__ outT, int use_ws)
{
  __shared__ __align__(16) unsigned char lds[BATCH * CIN * 2 + 4 * 2 * WSLICE]; // 64 KB
  ushort* lA        = (ushort*)lds;
  unsigned char* lW = lds + BATCH * CIN * 2;

  const int g    = blockIdx.x;
  const int tid  = threadIdx.x;
  const int wave = tid >> 6;
  const int lane = tid & 63;

  // ---- A DMA: wave w stages b-rows [16w,16w+16); 8 issues x 1KB ----
#pragma unroll
  for (int j = 0; j < 8; ++j) {
    int b = 16 * wave + 2 * j + (lane >> 5);
    const ushort* gsrc = xT + ((size_t)b * GN + g) * CIN + (lane & 31) * 8;
    ushort* ldst = lA + (16 * wave + 2 * j) * CIN;
    gload16(gsrc, ldst);
  }

  const float* wg = W + ((size_t)g * COUT + 64 * wave) * CIN;
  const int swz_src = ((lane & 7) ^ (lane >> 3)) << 4;
  const int wrow    = lane >> 3;

  unsigned char* lWw = lW + wave * (2 * WSLICE);

  // stage 32-row x 32-k W slice into per-wave buf
  auto stage_w = [&](const float* half_base, int ks, int buf) {
    unsigned char* ldb = lWw + buf * WSLICE;
    const unsigned char* gb = (const unsigned char*)half_base + (size_t)ks * 128 + swz_src;
#pragma unroll
    for (int j = 0; j < 4; ++j) {
      gload16(gb + (size_t)(8 * j + wrow) * (CIN * 4), ldb + j * 1024);
    }
  };

  const int arow = lane & 15;
  const int colk = (lane >> 4) * 32;
  const int kq   = (lane >> 4) << 3;

  f32x4 acc[4][4];
#pragma unroll
  for (int m = 0; m < 4; ++m)
#pragma unroll
    for (int n = 0; n < 4; ++n)
      acc[m][n] = {0.f, 0.f, 0.f, 0.f};

#pragma unroll
  for (int oh = 0; oh < 2; ++oh) {
    const float* half_base = wg + (size_t)(32 * oh) * CIN;
    stage_w(half_base, 0, 0);
    stage_w(half_base, 1, 1);

    if (oh == 0) {
      // retire A (oldest 8 of 16); W0/W1 stay in flight across the barrier
      asm volatile("s_waitcnt vmcnt(8)" ::: "memory");
      __builtin_amdgcn_sched_barrier(0);
      __builtin_amdgcn_s_barrier();
    }

#pragma unroll
    for (int ks = 0; ks < 8; ++ks) {
      if (ks < 7) { asm volatile("s_waitcnt vmcnt(4)" ::: "memory"); }
      else        { asm volatile("s_waitcnt vmcnt(0)" ::: "memory"); }
      __builtin_amdgcn_sched_barrier(0);

      unsigned char* wb = lWw + (ks & 1) * WSLICE;
      const int key = (arow & 7) << 4;

      // LDS reads for this sub-iteration
      float4 f[2][2];
#pragma unroll
      for (int n2 = 0; n2 < 2; ++n2) {
        int r = n2 * 16 + arow;
        f[n2][0] = *reinterpret_cast<const float4*>(wb + r * 128 + (colk ^ key));
        f[n2][1] = *reinterpret_cast<const float4*>(wb + r * 128 + ((colk + 16) ^ key));
      }
      bf16x8 afr[4];
      const int i0 = ks * 32 + kq;
#pragma unroll
      for (int m = 0; m < 4; ++m) {
        int row = m * 16 + arow;
        afr[m] = *reinterpret_cast<const bf16x8*>(
            &lA[row * CIN + (i0 ^ ((row & 7) << 3))]);
      }

      // retire ds_reads, then overwrite the just-read buffer with DMA
      asm volatile("s_waitcnt lgkmcnt(0)" ::: "memory");
      __builtin_amdgcn_sched_barrier(0);
      if (ks < 6) stage_w(half_base, ks + 2, ks & 1);

      bf16x8 bfr[2];
#pragma unroll
      for (int n2 = 0; n2 < 2; ++n2) {
        bfr[n2][0] = (__bf16)f[n2][0].x; bfr[n2][1] = (__bf16)f[n2][0].y;
        bfr[n2][2] = (__bf16)f[n2][0].z; bfr[n2][3] = (__bf16)f[n2][0].w;
        bfr[n2][4] = (__bf16)f[n2][1].x; bfr[n2][5] = (__bf16)f[n2][1].y;
        bfr[n2][6] = (__bf16)f[n2][1].z; bfr[n2][7] = (__bf16)f[n2][1].w;
      }

      __builtin_amdgcn_s_setprio(1);
#pragma unroll
      for (int m = 0; m < 4; ++m)
#pragma unroll
        for (int n2 = 0; n2 < 2; ++n2)
          acc[m][2 * oh + n2] = __builtin_amdgcn_mfma_f32_16x16x32_bf16(
              afr[m], bfr[n2], acc[m][2 * oh + n2], 0, 0, 0);
      __builtin_amdgcn_s_setprio(0);
    }
  }

  const int oc = 64 * wave + arow;
  float bv[4];
#pragma unroll
  for (int n = 0; n < 4; ++n) bv[n] = bias[g * COUT + oc + n * 16];

  if (use_ws) {
#pragma unroll
    for (int m = 0; m < 4; ++m) {
#pragma unroll
      for (int n = 0; n < 4; ++n) {
        int o = oc + n * 16;
#pragma unroll
        for (int j = 0; j < 4; ++j) {
          int b = m * 16 + ((lane >> 4) << 2) + j;
          __hip_bfloat16 h = __float2bfloat16(acc[m][n][j] + bv[n]);
          outT[((size_t)b * GN + g) * COUT + o] = *reinterpret_cast<ushort*>(&h);
        }
      }
    }
  } else {
#pragma unroll
    for (int m = 0; m < 4; ++m) {
#pragma unroll
      for (int n = 0; n < 4; ++n) {
        int o = oc + n * 16;
#pragma unroll
        for (int j = 0; j < 4; ++j) {
          int b = m * 16 + ((lane >> 4) << 2) + j;
          out[((size_t)b * COUT + o) * GN + g] = acc[m][n][j] + bv[n];
        }
      }
    }
  }
}

// ---------------------------------------------------------------------------
// Kernel 3: transpose  outT[b][g][o] (bf16) -> out[b][o][g] (f32)
// ---------------------------------------------------------------------------
__global__ __launch_bounds__(256) void k_transpose_out(
    const ushort* __restrict__ outT, float* __restrict__ out)
{
  __shared__ float tile[64][65];  // [g][o]
  const int g0 = blockIdx.x * 64;
  const int o0 = blockIdx.y * 64;
  const int b  = blockIdx.z;
  const int t  = threadIdx.x;
  const int a  = t & 15;
  const int r  = t >> 4;

  const ushort* src = outT + (size_t)b * GN * COUT;
#pragma unroll
  for (int p = 0; p < 4; ++p) {
    int gl = p * 16 + r;
    ushort4 u = *reinterpret_cast<const ushort4*>(
        &src[(size_t)(g0 + gl) * COUT + o0 + a * 4]);
    tile[gl][a * 4 + 0] = bf2f(u.x);
    tile[gl][a * 4 + 1] = bf2f(u.y);
    tile[gl][a * 4 + 2] = bf2f(u.z);
    tile[gl][a * 4 + 3] = bf2f(u.w);
  }
  __syncthreads();

  float* dst = out + (size_t)b * COUT * GN;
#pragma unroll
  for (int p = 0; p < 4; ++p) {
    int ol = p * 16 + r;
    float4 v;
    v.x = tile[a * 4 + 0][ol];
    v.y = tile[a * 4 + 1][ol];
    v.z = tile[a * 4 + 2][ol];
    v.w = tile[a * 4 + 3][ol];
    *reinterpret_cast<float4*>(&dst[(size_t)(o0 + ol) * GN + g0 + a * 4]) = v;
  }
}

// ---------------------------------------------------------------------------
extern "C" void kernel_launch(void* const* d_in, const int* in_sizes, int n_in,
                              void* d_out, int out_size, void* d_ws, size_t ws_size,
                              hipStream_t stream) {
  const float* x  = (const float*)d_in[0];
  const float* W  = (const float*)d_in[1];
  const float* bs = (const float*)d_in[2];
  float* out      = (float*)d_out;

  const size_t xT_elems = (size_t)BATCH * GN * CIN;
  const size_t oT_elems = (size_t)BATCH * GN * COUT;
  const bool use_ws = ws_size >= (xT_elems + oT_elems) * sizeof(ushort);

  ushort* xT   = (ushort*)d_ws;
  ushort* outT = xT + xT_elems;

  dim3 grid1(GN / 64, CIN / 64, BATCH);
  k_transpose_convert<<<grid1, 256, 0, stream>>>(x, xT);
  k_group_gemm<<<GN, 256, 0, stream>>>(xT, W, bs, out,
                                       use_ws ? outT : nullptr,
                                       use_ws ? 1 : 0);
  if (use_ws) {
    dim3 grid3(GN / 64, COUT / 64, BATCH);
    k_transpose_out<<<grid3, 256, 0, stream>>>(outT, out);
  }
}

// Round 6
// 111.189 us; speedup vs baseline: 1.0672x; 1.0672x over previous
//
#include <hip/hip_runtime.h>
#include <hip/hip_bf16.h>

typedef __bf16 bf16x8 __attribute__((ext_vector_type(8)));
typedef float f32x4 __attribute__((ext_vector_type(4)));

#define GN    1024
#define BATCH 64
#define CIN   256
#define COUT  256
#define NG    4                      // g's per persistent block
#define A_ELEMS (BATCH * CIN)        // 16384 ushorts = 32 KB
#define WSLICE  8192                 // per wave, per buffer: 64 o-rows x 32 k x 4B

#define G_AS __attribute__((address_space(1)))
#define L_AS __attribute__((address_space(3)))

static __device__ __forceinline__ void gload16(const void* g, void* l) {
  __builtin_amdgcn_global_load_lds((const G_AS void*)g, (L_AS void*)l, 16, 0, 0);
}

static __device__ __forceinline__ ushort f2bf(float f) {
  __hip_bfloat16 h = __float2bfloat16(f);
  return *reinterpret_cast<ushort*>(&h);
}
static __device__ __forceinline__ float bf2f(ushort u) {
  uint v = (uint)u << 16;
  return *reinterpret_cast<float*>(&v);
}

// ---------------------------------------------------------------------------
// Kernel 1: transpose + convert  x[b][i][g] (f32) -> xT[b][g][i^((b&7)<<3)] (bf16)
// xT stored PRE-SWIZZLED in i so k2 can DMA it linearly (rule 21).
// ---------------------------------------------------------------------------
__global__ __launch_bounds__(256) void k_transpose_convert(
    const float* __restrict__ x, ushort* __restrict__ xT)
{
  __shared__ float tile[64][65];
  const int g0 = blockIdx.x * 64;
  const int i0 = blockIdx.y * 64;
  const int b  = blockIdx.z;
  const int t  = threadIdx.x;
  const int a  = t & 15;
  const int r  = t >> 4;
  const int key = (b & 7) << 3;

  const float* xb = x + (size_t)b * CIN * GN;
#pragma unroll
  for (int p = 0; p < 4; ++p) {
    int ii = p * 16 + r;
    float4 v = *reinterpret_cast<const float4*>(
        &xb[(size_t)(i0 + ii) * GN + g0 + a * 4]);
    tile[ii][a * 4 + 0] = v.x;
    tile[ii][a * 4 + 1] = v.y;
    tile[ii][a * 4 + 2] = v.z;
    tile[ii][a * 4 + 3] = v.w;
  }
  __syncthreads();

  ushort* xTb = xT + (size_t)b * GN * CIN;
#pragma unroll
  for (int p = 0; p < 4; ++p) {
    int gg = p * 16 + r;
    ushort4 u;
    u.x = f2bf(tile[a * 4 + 0][gg]);
    u.y = f2bf(tile[a * 4 + 1][gg]);
    u.z = f2bf(tile[a * 4 + 2][gg]);
    u.w = f2bf(tile[a * 4 + 3][gg]);
    int isw = (i0 + a * 4) ^ key;
    *reinterpret_cast<ushort4*>(&xTb[(size_t)(g0 + gg) * CIN + isw]) = u;
  }
}

// ---------------------------------------------------------------------------
// Kernel 2: PERSISTENT per-group GEMM. grid = GN/NG = 256 blocks (1/CU).
// Each block: NG=4 consecutive g's in one DMA-paced pipeline.
//   A: 2 x 32 KB dbuf (A(g+1) DMA'd during g's ks=5).
//   W: per-wave 2 x 8 KB dbuf, counted vmcnt pacing, one raw s_barrier per g.
// vmcnt bookkeeping (per wave, oldest-first queue):
//   g-start invariant: outstanding = W1(g) = 8.
//   ks=0..5: vmcnt(8); stage W(ks+2) after lgkm0 (ks<6); ks=5 also stages A'.
//   ks=6: vmcnt(16) [A' in stream] / vmcnt(8) on last g.
//   ks=7: vmcnt(8) [leaves A'] / vmcnt(0) on last g.
//   epilogue: 16 stores, then W0',W1' (16 loads) -> vmcnt(8) retires
//   A'(8)+stores(16)+W0'(8), leaving W1' = 8. barrier. invariant restored.
// ---------------------------------------------------------------------------
__global__ __launch_bounds__(256) void k_group_gemm(
    const ushort* __restrict__ xT, const float* __restrict__ W,
    const float* __restrict__ bias, float* __restrict__ out,
    ushort* __restrict__ outT, int use_ws)
{
  __shared__ __align__(16) unsigned char lds[2 * A_ELEMS * 2 + 4 * 2 * WSLICE]; // 128 KB
  ushort* lA        = (ushort*)lds;
  unsigned char* lW = lds + 2 * A_ELEMS * 2;

  const int tid  = threadIdx.x;
  const int wave = tid >> 6;
  const int lane = tid & 63;
  const int g_base = blockIdx.x * NG;

  const int arow = lane & 15;
  const int colk = (lane >> 4) * 32;
  const int kq   = (lane >> 4) << 3;
  const int oc   = 64 * wave + arow;

  unsigned char* lWw = lW + wave * (2 * WSLICE);
  const int swz_src = ((lane & 7) ^ (lane >> 3)) << 4;
  const int wrow    = lane >> 3;

  auto stage_a = [&](int gg, int ab) {
    ushort* base = lA + ab * A_ELEMS;
#pragma unroll
    for (int j = 0; j < 8; ++j) {
      int b = 16 * wave + 2 * j + (lane >> 5);
      const ushort* gsrc = xT + ((size_t)b * GN + gg) * CIN + (lane & 31) * 8;
      gload16(gsrc, base + (16 * wave + 2 * j) * CIN);
    }
  };
  auto stage_w = [&](const float* wgp, int ks, int buf) {
    unsigned char* ldb = lWw + buf * WSLICE;
    const unsigned char* gb = (const unsigned char*)wgp + (size_t)ks * 128 + swz_src;
#pragma unroll
    for (int j = 0; j < 8; ++j) {
      gload16(gb + (size_t)(8 * j + wrow) * (CIN * 4), ldb + j * 1024);
    }
  };

  // ---- prologue: bias preload (16 loads), A(g0), W0, W1 ----
  float bvv[NG][4];
#pragma unroll
  for (int gi = 0; gi < NG; ++gi)
#pragma unroll
    for (int n = 0; n < 4; ++n)
      bvv[gi][n] = bias[(g_base + gi) * COUT + oc + n * 16];
  __builtin_amdgcn_sched_barrier(0);

  stage_a(g_base, 0);
  __builtin_amdgcn_sched_barrier(0);
  {
    const float* wg0 = W + ((size_t)g_base * COUT + 64 * wave) * CIN;
    stage_w(wg0, 0, 0);
    __builtin_amdgcn_sched_barrier(0);
    stage_w(wg0, 1, 1);
    __builtin_amdgcn_sched_barrier(0);
  }
  // out = bias16 + A8 + W0:8 + W1:8 = 40; retire oldest 32, keep W1
  asm volatile("s_waitcnt vmcnt(8)" ::: "memory");
  __builtin_amdgcn_sched_barrier(0);
  __builtin_amdgcn_s_barrier();

#pragma unroll
  for (int gi = 0; gi < NG; ++gi) {
    const int g = g_base + gi;
    const ushort* lAc = lA + (gi & 1) * A_ELEMS;
    const float* wgp  = W + ((size_t)g * COUT + 64 * wave) * CIN;

    f32x4 acc[4][4];
#pragma unroll
    for (int m = 0; m < 4; ++m)
#pragma unroll
      for (int n = 0; n < 4; ++n)
        acc[m][n] = {0.f, 0.f, 0.f, 0.f};

#pragma unroll
    for (int ks = 0; ks < 8; ++ks) {
      if (gi < NG - 1) {
        if (ks == 6) { asm volatile("s_waitcnt vmcnt(16)" ::: "memory"); }
        else         { asm volatile("s_waitcnt vmcnt(8)"  ::: "memory"); }
      } else {
        if (ks == 7) { asm volatile("s_waitcnt vmcnt(0)"  ::: "memory"); }
        else         { asm volatile("s_waitcnt vmcnt(8)"  ::: "memory"); }
      }
      __builtin_amdgcn_sched_barrier(0);

      unsigned char* wb = lWw + (ks & 1) * WSLICE;
      const int key = (arow & 7) << 4;

      float4 f[4][2];
#pragma unroll
      for (int n = 0; n < 4; ++n) {
        int r = n * 16 + arow;
        f[n][0] = *reinterpret_cast<const float4*>(wb + r * 128 + (colk ^ key));
        f[n][1] = *reinterpret_cast<const float4*>(wb + r * 128 + ((colk + 16) ^ key));
      }
      bf16x8 afr[4];
      const int i0 = ks * 32 + kq;
#pragma unroll
      for (int m = 0; m < 4; ++m) {
        int row = m * 16 + arow;
        afr[m] = *reinterpret_cast<const bf16x8*>(
            &lAc[row * CIN + (i0 ^ ((row & 7) << 3))]);
      }

      asm volatile("s_waitcnt lgkmcnt(0)" ::: "memory");
      __builtin_amdgcn_sched_barrier(0);
      if (ks < 6) stage_w(wgp, ks + 2, ks & 1);
      if (ks == 5 && gi < NG - 1) stage_a(g + 1, (gi & 1) ^ 1);
      __builtin_amdgcn_sched_barrier(0);

      bf16x8 bfr[4];
#pragma unroll
      for (int n = 0; n < 4; ++n) {
        bfr[n][0] = (__bf16)f[n][0].x; bfr[n][1] = (__bf16)f[n][0].y;
        bfr[n][2] = (__bf16)f[n][0].z; bfr[n][3] = (__bf16)f[n][0].w;
        bfr[n][4] = (__bf16)f[n][1].x; bfr[n][5] = (__bf16)f[n][1].y;
        bfr[n][6] = (__bf16)f[n][1].z; bfr[n][7] = (__bf16)f[n][1].w;
      }

      __builtin_amdgcn_s_setprio(1);
#pragma unroll
      for (int m = 0; m < 4; ++m)
#pragma unroll
        for (int n = 0; n < 4; ++n)
          acc[m][n] = __builtin_amdgcn_mfma_f32_16x16x32_bf16(
              afr[m], bfr[n], acc[m][n], 0, 0, 0);
      __builtin_amdgcn_s_setprio(0);
    }

    // ---- epilogue for g: exactly 16 stores (counted in vmcnt stream) ----
    if (use_ws) {
#pragma unroll
      for (int m = 0; m < 4; ++m) {
#pragma unroll
        for (int n = 0; n < 4; ++n) {
          int o = oc + n * 16;
#pragma unroll
          for (int j = 0; j < 4; ++j) {
            int b = m * 16 + ((lane >> 4) << 2) + j;
            __hip_bfloat16 h = __float2bfloat16(acc[m][n][j] + bvv[gi][n]);
            outT[((size_t)b * GN + g) * COUT + o] = *reinterpret_cast<ushort*>(&h);
          }
        }
      }
    } else {
#pragma unroll
      for (int m = 0; m < 4; ++m) {
#pragma unroll
        for (int n = 0; n < 4; ++n) {
          int o = oc + n * 16;
#pragma unroll
          for (int j = 0; j < 4; ++j) {
            int b = m * 16 + ((lane >> 4) << 2) + j;
            out[((size_t)b * COUT + o) * GN + g] = acc[m][n][j] + bvv[gi][n];
          }
        }
      }
    }
    __builtin_amdgcn_sched_barrier(0);

    if (gi < NG - 1) {
      const float* wgn = W + ((size_t)(g + 1) * COUT + 64 * wave) * CIN;
      stage_w(wgn, 0, 0);
      __builtin_amdgcn_sched_barrier(0);
      stage_w(wgn, 1, 1);
      __builtin_amdgcn_sched_barrier(0);
      // out = A'(8) + stores(16) + W0'(8) + W1'(8) = 40 -> keep W1' only
      asm volatile("s_waitcnt vmcnt(8)" ::: "memory");
      __builtin_amdgcn_sched_barrier(0);
      __builtin_amdgcn_s_barrier();
    }
  }
}

// ---------------------------------------------------------------------------
// Kernel 3: transpose  outT[b][g][o] (bf16) -> out[b][o][g] (f32)
// ---------------------------------------------------------------------------
__global__ __launch_bounds__(256) void k_transpose_out(
    const ushort* __restrict__ outT, float* __restrict__ out)
{
  __shared__ float tile[64][65];  // [g][o]
  const int g0 = blockIdx.x * 64;
  const int o0 = blockIdx.y * 64;
  const int b  = blockIdx.z;
  const int t  = threadIdx.x;
  const int a  = t & 15;
  const int r  = t >> 4;

  const ushort* src = outT + (size_t)b * GN * COUT;
#pragma unroll
  for (int p = 0; p < 4; ++p) {
    int gl = p * 16 + r;
    ushort4 u = *reinterpret_cast<const ushort4*>(
        &src[(size_t)(g0 + gl) * COUT + o0 + a * 4]);
    tile[gl][a * 4 + 0] = bf2f(u.x);
    tile[gl][a * 4 + 1] = bf2f(u.y);
    tile[gl][a * 4 + 2] = bf2f(u.z);
    tile[gl][a * 4 + 3] = bf2f(u.w);
  }
  __syncthreads();

  float* dst = out + (size_t)b * COUT * GN;
#pragma unroll
  for (int p = 0; p < 4; ++p) {
    int ol = p * 16 + r;
    float4 v;
    v.x = tile[a * 4 + 0][ol];
    v.y = tile[a * 4 + 1][ol];
    v.z = tile[a * 4 + 2][ol];
    v.w = tile[a * 4 + 3][ol];
    *reinterpret_cast<float4*>(&dst[(size_t)(o0 + ol) * GN + g0 + a * 4]) = v;
  }
}

// ---------------------------------------------------------------------------
extern "C" void kernel_launch(void* const* d_in, const int* in_sizes, int n_in,
                              void* d_out, int out_size, void* d_ws, size_t ws_size,
                              hipStream_t stream) {
  const float* x  = (const float*)d_in[0];
  const float* W  = (const float*)d_in[1];
  const float* bs = (const float*)d_in[2];
  float* out      = (float*)d_out;

  const size_t xT_elems = (size_t)BATCH * GN * CIN;
  const size_t oT_elems = (size_t)BATCH * GN * COUT;
  const bool use_ws = ws_size >= (xT_elems + oT_elems) * sizeof(ushort);

  ushort* xT   = (ushort*)d_ws;
  ushort* outT = xT + xT_elems;

  dim3 grid1(GN / 64, CIN / 64, BATCH);
  k_transpose_convert<<<grid1, 256, 0, stream>>>(x, xT);
  k_group_gemm<<<GN / NG, 256, 0, stream>>>(xT, W, bs, out,
                                            use_ws ? outT : nullptr,
                                            use_ws ? 1 : 0);
  if (use_ws) {
    dim3 grid3(GN / 64, COUT / 64, BATCH);
    k_transpose_out<<<grid3, 256, 0, stream>>>(outT, out);
  }
}